// Round 1
// baseline (12297.545 us; speedup 1.0000x reference)
//
#include <hip/hip_runtime.h>

// Grid_Block: [B,C,H,W]=[8,256,128,128], grid window 8x8 (N=64 tokens), NH=8, hd=32.
// Pipeline: K1 attn(per-window fused) -> u in d_out ; K2 conv1+bn+gelu -> m1(bf16) in ws ;
//           K3 conv2+bn+gelu + u residual -> d_out.

#define DI __device__ __forceinline__

DI unsigned short f2bf(float f) {
    unsigned u = __float_as_uint(f);
    u = u + 0x7FFFu + ((u >> 16) & 1u);   // round-to-nearest-even
    return (unsigned short)(u >> 16);
}
DI float bf2f(unsigned short s) { return __uint_as_float(((unsigned)s) << 16); }

// ----------------------------- attention kernel ------------------------------
// one block per window (b, hp, wp); 256 threads = 4 waves
__global__ __launch_bounds__(256, 1) void attn_win_kernel(
    const float* __restrict__ x, const float* __restrict__ ln1g, const float* __restrict__ ln1b,
    const float* __restrict__ qkvw, const float* __restrict__ relt,
    const float* __restrict__ ln2g, const float* __restrict__ ln2b,
    float* __restrict__ uout)
{
    __shared__ unsigned short hs[64][264];   // LN1 output, bf16        (33.8 KB)
    __shared__ float outs[64][258];          // g, then g+o (residual)  (66.0 KB)
    __shared__ float qs[64][36], ks[64][36], vs[64][36];  // per-head   (27.6 KB)

    const int win = blockIdx.x;
    const int b = win >> 8, hp = (win >> 4) & 15, wp = win & 15;
    const int t = threadIdx.x, lane = t & 63, wv = t >> 6;

    // ---- Phase 1: gather g + LN1 ----
    for (int n = wv; n < 64; n += 4) {
        const int gh = n >> 3, gw = n & 7;
        const int hh = gh * 16 + hp, ww = gw * 16 + wp;
        const float* xp = x + ((size_t)(b * 256) * 128 + hh) * 128 + ww;
        float v0 = xp[(size_t)(lane) * 16384];
        float v1 = xp[(size_t)(lane + 64) * 16384];
        float v2 = xp[(size_t)(lane + 128) * 16384];
        float v3 = xp[(size_t)(lane + 192) * 16384];
        float s = v0 + v1 + v2 + v3;
        float ss = v0 * v0 + v1 * v1 + v2 * v2 + v3 * v3;
        #pragma unroll
        for (int off = 32; off >= 1; off >>= 1) {
            s  += __shfl_xor(s, off);
            ss += __shfl_xor(ss, off);
        }
        float mean = s * (1.f / 256.f);
        float var  = ss * (1.f / 256.f) - mean * mean;
        float rstd = rsqrtf(var + 1e-5f);
        float vv[4] = {v0, v1, v2, v3};
        #pragma unroll
        for (int j = 0; j < 4; ++j) {
            int c = lane + j * 64;
            float g = vv[j];
            outs[n][c] = g;
            float h = (g - mean) * rstd * ln1g[c] + ln1b[c];
            hs[n][c] = f2bf(h);
        }
    }
    __syncthreads();

    const float scale = 0.17677669529663687f;  // 1/sqrt(32)

    for (int head = 0; head < 8; ++head) {
        // ---- Phase 2: qkv GEMM for this head ----
        {
            const int n = lane, grp = wv;   // 96 (which,dd) outputs split 24 per wave
            float acc[24];
            const float* wrow[24];
            #pragma unroll
            for (int o = 0; o < 24; ++o) {
                acc[o] = 0.f;
                int combo = grp * 24 + o;
                int which = combo >> 5, dd = combo & 31;
                wrow[o] = qkvw + (size_t)(which * 256 + head * 32 + dd) * 256;
            }
            for (int c = 0; c < 256; c += 4) {
                ushort4 hv = *(const ushort4*)&hs[n][c];
                float h0 = bf2f(hv.x), h1 = bf2f(hv.y), h2 = bf2f(hv.z), h3 = bf2f(hv.w);
                #pragma unroll
                for (int o = 0; o < 24; ++o) {
                    float4 w4 = *(const float4*)(wrow[o] + c);
                    acc[o] += h0 * w4.x + h1 * w4.y + h2 * w4.z + h3 * w4.w;
                }
            }
            #pragma unroll
            for (int o = 0; o < 24; ++o) {
                int combo = grp * 24 + o;
                int which = combo >> 5, dd = combo & 31;
                if (which == 0)      qs[n][dd] = acc[o];
                else if (which == 1) ks[n][dd] = acc[o];
                else                 vs[n][dd] = acc[o];
            }
        }
        __syncthreads();
        // ---- Phase 3: cosine-normalize q and k rows (no eps, matches ref) ----
        if (t < 128) {
            float* row = (t < 64) ? qs[t] : ks[t - 64];
            float sum = 0.f;
            #pragma unroll
            for (int dd = 0; dd < 32; ++dd) { float q = row[dd]; sum += q * q; }
            float inv = rsqrtf(sum);
            #pragma unroll
            for (int dd = 0; dd < 32; ++dd) row[dd] *= inv;
        }
        __syncthreads();
        // ---- Phase 4: scores + bias + softmax + PV ----
        {
            const int rowi = lane >> 2, cg = lane & 3;
            const int n = wv * 16 + rowi;
            const int ghn = n >> 3, gwn = n & 7;
            float qreg[32];
            #pragma unroll
            for (int d4 = 0; d4 < 32; d4 += 4) {
                float4 q4 = *(const float4*)&qs[n][d4];
                qreg[d4] = q4.x; qreg[d4 + 1] = q4.y; qreg[d4 + 2] = q4.z; qreg[d4 + 3] = q4.w;
            }
            float sc[16];
            #pragma unroll
            for (int j = 0; j < 16; ++j) {
                int m = cg * 16 + j;
                float d = 0.f;
                #pragma unroll
                for (int d4 = 0; d4 < 32; d4 += 4) {
                    float4 k4 = *(const float4*)&ks[m][d4];
                    d += qreg[d4] * k4.x + qreg[d4 + 1] * k4.y + qreg[d4 + 2] * k4.z + qreg[d4 + 3] * k4.w;
                }
                int ghm = m >> 3, gwm = m & 7;
                int ridx = (ghn - ghm + 7) * 15 + (gwn - gwm + 7);
                sc[j] = d * scale + relt[ridx * 8 + head];
            }
            float mx = sc[0];
            #pragma unroll
            for (int j = 1; j < 16; ++j) mx = fmaxf(mx, sc[j]);
            mx = fmaxf(mx, __shfl_xor(mx, 1));
            mx = fmaxf(mx, __shfl_xor(mx, 2));
            float sum = 0.f;
            #pragma unroll
            for (int j = 0; j < 16; ++j) { sc[j] = __expf(sc[j] - mx); sum += sc[j]; }
            sum += __shfl_xor(sum, 1);
            sum += __shfl_xor(sum, 2);
            float inv = 1.f / sum;
            float ov[32];
            #pragma unroll
            for (int d = 0; d < 32; ++d) ov[d] = 0.f;
            #pragma unroll
            for (int j = 0; j < 16; ++j) {
                int m = cg * 16 + j;
                float a = sc[j] * inv;
                #pragma unroll
                for (int d4 = 0; d4 < 32; d4 += 4) {
                    float4 v4 = *(const float4*)&vs[m][d4];
                    ov[d4] += a * v4.x; ov[d4 + 1] += a * v4.y;
                    ov[d4 + 2] += a * v4.z; ov[d4 + 3] += a * v4.w;
                }
            }
            #pragma unroll
            for (int d = 0; d < 32; ++d) {
                ov[d] += __shfl_xor(ov[d], 1);
                ov[d] += __shfl_xor(ov[d], 2);
            }
            #pragma unroll
            for (int i = 0; i < 8; ++i) {
                int dd = cg * 8 + i;
                outs[n][head * 32 + dd] += ov[dd];
            }
        }
        __syncthreads();
    }

    // ---- Phase 5: LN2 + scatter u to NCHW ----
    for (int n = wv; n < 64; n += 4) {
        const int gh = n >> 3, gw = n & 7;
        float v0 = outs[n][lane], v1 = outs[n][lane + 64];
        float v2 = outs[n][lane + 128], v3 = outs[n][lane + 192];
        float s = v0 + v1 + v2 + v3;
        float ss = v0 * v0 + v1 * v1 + v2 * v2 + v3 * v3;
        #pragma unroll
        for (int off = 32; off >= 1; off >>= 1) {
            s  += __shfl_xor(s, off);
            ss += __shfl_xor(ss, off);
        }
        float mean = s * (1.f / 256.f);
        float var  = ss * (1.f / 256.f) - mean * mean;
        float rstd = rsqrtf(var + 1e-5f);
        const int hh = gh * 16 + hp, ww = gw * 16 + wp;
        float vv[4] = {v0, v1, v2, v3};
        #pragma unroll
        for (int j = 0; j < 4; ++j) {
            int c = lane + j * 64;
            float u = (vv[j] - mean) * rstd * ln2g[c] + ln2b[c];
            uout[((size_t)(b * 256 + c) * 128 + hh) * 128 + ww] = u;
        }
    }
}

// ------------------------- conv3x3 + BN + GELU kernel ------------------------
// MODE 1: f32 src -> bf16 dst.  MODE 2: bf16 src -> f32 dst with residual add.
// block: 16x16 spatial x 32 oc tile; 256 threads, acc[4 rows][8 oc] per thread.
template <int MODE>
__global__ __launch_bounds__(256, 2) void conv_bn_gelu_kernel(
    const void* __restrict__ src_, const float* __restrict__ cw,
    const float* __restrict__ bng, const float* __restrict__ bnb,
    const float* __restrict__ bnm, const float* __restrict__ bnv,
    void* __restrict__ dst_, const float* __restrict__ resid)
{
    __shared__ float in_s[32][18][18];   // 41.5 KB  (ci chunk with halo, pad offset -1)
    __shared__ float w_s[32][9][32];     // 36.9 KB  [ci][k][oc]

    const int id = blockIdx.x;
    const int txl = id & 7, tyl = (id >> 3) & 7, oct = (id >> 6) & 7, b = id >> 9;
    const int h0 = tyl * 16, w0 = txl * 16;
    const int t = threadIdx.x;
    const int tx = t & 15, tyg = (t >> 4) & 3, ocg = t >> 6;

    float acc[4][8];
    #pragma unroll
    for (int j = 0; j < 4; ++j)
        #pragma unroll
        for (int p = 0; p < 8; ++p) acc[j][p] = 0.f;

    const float* srcf = (const float*)src_;
    const unsigned short* srcb = (const unsigned short*)src_;

    for (int cb = 0; cb < 8; ++cb) {
        // stage input chunk 32ci x 18 x 18 (zero-padded SAME borders)
        for (int idx = t; idx < 10368; idx += 256) {
            int ci = idx / 324; int r = idx - ci * 324;
            int y = r / 18; int xx = r - y * 18;
            int gy = h0 + y - 1, gx = w0 + xx - 1;
            float val = 0.f;
            if (gy >= 0 && gy < 128 && gx >= 0 && gx < 128) {
                size_t gidx = ((size_t)(b * 256 + cb * 32 + ci) * 128 + gy) * 128 + gx;
                val = (MODE == 1) ? srcf[gidx] : bf2f(srcb[gidx]);
            }
            in_s[ci][y][xx] = val;
        }
        // stage weights 32oc x 32ci x 9  ->  w_s[ci][k][oc]
        for (int idx = t; idx < 9216; idx += 256) {
            int oc = idx / 288; int r = idx - oc * 288;
            int ci = r / 9; int k = r - ci * 9;
            w_s[ci][k][oc] = cw[((size_t)(oct * 32 + oc) * 256 + cb * 32 + ci) * 9 + k];
        }
        __syncthreads();

        #pragma unroll 1
        for (int ci = 0; ci < 32; ++ci) {
            #pragma unroll
            for (int k = 0; k < 9; ++k) {
                const int ky = k / 3, kx = k - ky * 3;
                float4 wa = *(const float4*)&w_s[ci][k][ocg * 8];
                float4 wb = *(const float4*)&w_s[ci][k][ocg * 8 + 4];
                #pragma unroll
                for (int j = 0; j < 4; ++j) {
                    float iv = in_s[ci][tyg + 4 * j + ky][tx + kx];
                    acc[j][0] += iv * wa.x; acc[j][1] += iv * wa.y;
                    acc[j][2] += iv * wa.z; acc[j][3] += iv * wa.w;
                    acc[j][4] += iv * wb.x; acc[j][5] += iv * wb.y;
                    acc[j][6] += iv * wb.z; acc[j][7] += iv * wb.w;
                }
            }
        }
        __syncthreads();
    }

    // epilogue: BN (eval) + exact GELU (+ residual for MODE 2)
    #pragma unroll
    for (int p = 0; p < 8; ++p) {
        int oc = oct * 32 + ocg * 8 + p;
        float scl = bng[oc] * rsqrtf(bnv[oc] + 1e-5f);
        float sh  = bnb[oc] - bnm[oc] * scl;
        #pragma unroll
        for (int j = 0; j < 4; ++j) {
            int y = h0 + tyg + 4 * j, xx2 = w0 + tx;
            float v = acc[j][p] * scl + sh;
            float ge = 0.5f * v * (1.f + erff(v * 0.70710678118654752f));
            size_t gidx = ((size_t)(b * 256 + oc) * 128 + y) * 128 + xx2;
            if (MODE == 1) ((unsigned short*)dst_)[gidx] = f2bf(ge);
            else           ((float*)dst_)[gidx] = ge + resid[gidx];
        }
    }
}

// --------------------------------- launcher ----------------------------------
extern "C" void kernel_launch(void* const* d_in, const int* in_sizes, int n_in,
                              void* d_out, int out_size, void* d_ws, size_t ws_size,
                              hipStream_t stream)
{
    const float* x    = (const float*)d_in[0];
    const float* ln1g = (const float*)d_in[1];
    const float* ln1b = (const float*)d_in[2];
    const float* qkvw = (const float*)d_in[3];
    const float* relt = (const float*)d_in[4];
    const float* ln2g = (const float*)d_in[5];
    const float* ln2b = (const float*)d_in[6];
    const float* c1w  = (const float*)d_in[7];
    const float* bn1g = (const float*)d_in[8];
    const float* bn1b = (const float*)d_in[9];
    const float* bn1m = (const float*)d_in[10];
    const float* bn1v = (const float*)d_in[11];
    const float* c2w  = (const float*)d_in[12];
    const float* bn2g = (const float*)d_in[13];
    const float* bn2b = (const float*)d_in[14];
    const float* bn2m = (const float*)d_in[15];
    const float* bn2v = (const float*)d_in[16];

    float* out = (float*)d_out;
    unsigned short* m1 = (unsigned short*)d_ws;   // bf16 m1: 8*256*128*128*2 = 67 MB

    // K1: fused grid-attention block -> u (fp32, NCHW) into d_out
    attn_win_kernel<<<2048, 256, 0, stream>>>(x, ln1g, ln1b, qkvw, relt, ln2g, ln2b, out);
    // K2: m1 = gelu(bn1(conv1(u)))  (bf16 into ws)
    conv_bn_gelu_kernel<1><<<4096, 256, 0, stream>>>(out, c1w, bn1g, bn1b, bn1m, bn1v,
                                                     (void*)m1, nullptr);
    // K3: out = gelu(bn2(conv2(m1))) + u   (in-place over d_out)
    conv_bn_gelu_kernel<2><<<4096, 256, 0, stream>>>((const void*)m1, c2w, bn2g, bn2b, bn2m, bn2v,
                                                     (void*)out, out);
}

// Round 3
// 6998.530 us; speedup vs baseline: 1.7572x; 1.7572x over previous
//
#include <hip/hip_runtime.h>

// Grid_Block: [B,C,H,W]=[8,256,128,128], window 8x8 (N=64), NH=8, hd=32.
// K0 cvt_w: qkv_w fp32->bf16 (ws). K1 gather+LN1 -> h bf16 [131072,256] (ws).
// K2 attn: per-window, MFMA QKV GEMM + per-head online-softmax attention + LN2 -> u (d_out).
// K3 conv1+bn+gelu -> m1 bf16 (ws, aliases h). K4 conv2+bn+gelu + residual -> d_out.

#define DI __device__ __forceinline__
typedef __attribute__((ext_vector_type(8))) short bf16x8;
typedef __attribute__((ext_vector_type(4))) float f32x4;

DI unsigned short f2bf(float f) {
    unsigned u = __float_as_uint(f);
    u = u + 0x7FFFu + ((u >> 16) & 1u);   // RNE
    return (unsigned short)(u >> 16);
}
DI float bf2f(unsigned short s) { return __uint_as_float(((unsigned)s) << 16); }
DI float bflo(unsigned u) { return __uint_as_float(u << 16); }
DI float bfhi(unsigned u) { return __uint_as_float(u & 0xFFFF0000u); }

// ------------------------------- K0: w -> bf16 -------------------------------
__global__ __launch_bounds__(256) void cvt_w_kernel(const float* __restrict__ w,
                                                    unsigned short* __restrict__ o) {
    int i = (blockIdx.x * 256 + threadIdx.x) * 4;   // grid 192 -> 196608 exact
    float4 f = *(const float4*)(w + i);
    ushort4 u;
    u.x = f2bf(f.x); u.y = f2bf(f.y); u.z = f2bf(f.z); u.w = f2bf(f.w);
    *(ushort4*)(o + i) = u;
}

// --------------------------- K1: gather + LN1 -> h ---------------------------
__global__ __launch_bounds__(256) void gather_ln1_kernel(
    const float* __restrict__ x, const float* __restrict__ g1, const float* __restrict__ b1,
    unsigned short* __restrict__ hglob)
{
    const int win = blockIdx.x;
    const int b = win >> 8, hp = (win >> 4) & 15, wp = win & 15;
    const int t = threadIdx.x, lane = t & 63, wv = t >> 6;

    for (int n = wv; n < 64; n += 4) {
        const int gh = n >> 3, gw = n & 7;
        const int hh = gh * 16 + hp, ww = gw * 16 + wp;
        const float* xp = x + ((size_t)(b * 256) * 128 + hh) * 128 + ww;
        float v0 = xp[(size_t)(lane) * 16384];
        float v1 = xp[(size_t)(lane + 64) * 16384];
        float v2 = xp[(size_t)(lane + 128) * 16384];
        float v3 = xp[(size_t)(lane + 192) * 16384];
        float s = v0 + v1 + v2 + v3;
        float ss = v0 * v0 + v1 * v1 + v2 * v2 + v3 * v3;
        #pragma unroll
        for (int off = 32; off >= 1; off >>= 1) {
            s  += __shfl_xor(s, off);
            ss += __shfl_xor(ss, off);
        }
        float mean = s * (1.f / 256.f);
        float var  = ss * (1.f / 256.f) - mean * mean;
        float rstd = rsqrtf(var + 1e-5f);
        unsigned short* hrow = hglob + ((size_t)win * 64 + n) * 256;
        float vv[4] = {v0, v1, v2, v3};
        #pragma unroll
        for (int j = 0; j < 4; ++j) {
            int c = lane + j * 64;
            hrow[c] = f2bf((vv[j] - mean) * rstd * g1[c] + b1[c]);
        }
    }
}

// ------------------------------ K2: attention --------------------------------
#define HS 264   // ushort row stride: 528 B = 33*16 (16B aligned), 132 dwords
__global__ __launch_bounds__(512, 1) void attn2_kernel(
    const float* __restrict__ x, const unsigned short* __restrict__ hglob,
    const unsigned short* __restrict__ wbf, const float* __restrict__ relt,
    const float* __restrict__ ln2g, const float* __restrict__ ln2b,
    float* __restrict__ uout)
{
    __shared__ unsigned short hbuf[64 * HS];   // h tile; reused as o (bf16) after GEMM
    __shared__ unsigned short qb[64 * HS];
    __shared__ unsigned short kb[64 * HS];
    __shared__ unsigned short vb[64 * HS];
    __shared__ float reltab[8][232];           // [head][ridx]
    __shared__ float rqs[64][8], rks[64][8];   // inverse norms

    const int win = blockIdx.x;
    const int b = win >> 8, hp = (win >> 4) & 15, wp = win & 15;
    const int t = threadIdx.x, lane = t & 63, wv = t >> 6;   // 8 waves
    const int l15 = lane & 15, l4 = lane >> 4;

    // ---- P1: coalesced h-tile load + rel-table transpose ----
    const unsigned short* hg = hglob + (size_t)win * 64 * 256;
    for (int i = t; i < 2048; i += 512) {            // 2048 x 16B = 32 KB
        int row = i >> 5, col8 = (i & 31) * 8;
        uint4 val = *(const uint4*)(hg + row * 256 + col8);
        *(uint4*)(hbuf + row * HS + col8) = val;
    }
    for (int i = t; i < 1800; i += 512) reltab[i & 7][i >> 3] = relt[i];
    __syncthreads();

    // ---- P2: QKV GEMM via MFMA (M=64, N=768, K=256); wave wv owns 6 N-tiles ----
    {
        f32x4 acc[4][6];
        #pragma unroll
        for (int mt = 0; mt < 4; ++mt)
            #pragma unroll
            for (int nt = 0; nt < 6; ++nt) acc[mt][nt] = (f32x4){0.f, 0.f, 0.f, 0.f};
        const int ntb = wv * 6;
        for (int kk = 0; kk < 8; ++kk) {
            bf16x8 afr[4];
            #pragma unroll
            for (int mt = 0; mt < 4; ++mt)
                afr[mt] = *(const bf16x8*)(hbuf + (mt * 16 + l15) * HS + kk * 32 + l4 * 8);
            #pragma unroll
            for (int nt = 0; nt < 6; ++nt) {
                int d = (ntb + nt) * 16 + l15;
                bf16x8 bfr = *(const bf16x8*)(wbf + d * 256 + kk * 32 + l4 * 8);
                #pragma unroll
                for (int mt = 0; mt < 4; ++mt)
                    acc[mt][nt] = __builtin_amdgcn_mfma_f32_16x16x32_bf16(afr[mt], bfr, acc[mt][nt], 0, 0, 0);
            }
        }
        // scatter C (bf16) into q/k/v LDS. C layout: col=lane&15, row=(lane>>4)*4+r
        #pragma unroll
        for (int nt = 0; nt < 6; ++nt) {
            int d = (ntb + nt) * 16 + l15;
            unsigned short* dst = (d < 256) ? qb : (d < 512 ? kb : vb);
            int dd = d & 255;
            #pragma unroll
            for (int mt = 0; mt < 4; ++mt)
                #pragma unroll
                for (int r = 0; r < 4; ++r) {
                    int n = mt * 16 + l4 * 4 + r;
                    dst[n * HS + dd] = f2bf(acc[mt][nt][r]);
                }
        }
    }
    __syncthreads();

    // ---- P3: cosine-norm factors (512 threads = 64 rows x 8 heads) ----
    {
        const int n = t & 63, hh = t >> 6;
        float sq = 0.f, sk = 0.f;
        #pragma unroll
        for (int j = 0; j < 32; j += 2) {
            unsigned uq = *(const unsigned*)(qb + n * HS + hh * 32 + j);
            unsigned uk = *(const unsigned*)(kb + n * HS + hh * 32 + j);
            float q0 = bflo(uq), q1 = bfhi(uq), k0 = bflo(uk), k1 = bfhi(uk);
            sq += q0 * q0 + q1 * q1;
            sk += k0 * k0 + k1 * k1;
        }
        rqs[n][hh] = rsqrtf(sq);
        rks[n][hh] = rsqrtf(sk);
    }
    __syncthreads();

    // ---- P4: per-head attention; wave = head, lane = query row; online softmax ----
    {
        const int h = wv, n = lane;
        const int ghn = n >> 3, gwn = n & 7;
        float qv[32];
        #pragma unroll
        for (int j = 0; j < 32; j += 2) {
            unsigned uq = *(const unsigned*)(qb + n * HS + h * 32 + j);
            qv[j] = bflo(uq); qv[j + 1] = bfhi(uq);
        }
        float qscale = rqs[n][h] * 0.17677669529663687f;   // rq * hd^-0.5
        #pragma unroll
        for (int j = 0; j < 32; ++j) qv[j] *= qscale;

        float M = -3.0e38f, L = 0.f;
        float ov[32];
        #pragma unroll
        for (int j = 0; j < 32; ++j) ov[j] = 0.f;

        #pragma unroll 4
        for (int m = 0; m < 64; ++m) {
            // dot(q, k[m]) -- k row broadcast from LDS
            uint4 k0 = *(const uint4*)(kb + m * HS + h * 32);
            uint4 k1 = *(const uint4*)(kb + m * HS + h * 32 + 8);
            uint4 k2 = *(const uint4*)(kb + m * HS + h * 32 + 16);
            uint4 k3 = *(const uint4*)(kb + m * HS + h * 32 + 24);
            float d0 = 0.f, d1 = 0.f, d2 = 0.f, d3 = 0.f;
            d0 += qv[0]*bflo(k0.x) + qv[1]*bfhi(k0.x) + qv[2]*bflo(k0.y) + qv[3]*bfhi(k0.y);
            d1 += qv[4]*bflo(k0.z) + qv[5]*bfhi(k0.z) + qv[6]*bflo(k0.w) + qv[7]*bfhi(k0.w);
            d2 += qv[8]*bflo(k1.x) + qv[9]*bfhi(k1.x) + qv[10]*bflo(k1.y) + qv[11]*bfhi(k1.y);
            d3 += qv[12]*bflo(k1.z) + qv[13]*bfhi(k1.z) + qv[14]*bflo(k1.w) + qv[15]*bfhi(k1.w);
            d0 += qv[16]*bflo(k2.x) + qv[17]*bfhi(k2.x) + qv[18]*bflo(k2.y) + qv[19]*bfhi(k2.y);
            d1 += qv[20]*bflo(k2.z) + qv[21]*bfhi(k2.z) + qv[22]*bflo(k2.w) + qv[23]*bfhi(k2.w);
            d2 += qv[24]*bflo(k3.x) + qv[25]*bfhi(k3.x) + qv[26]*bflo(k3.y) + qv[27]*bfhi(k3.y);
            d3 += qv[28]*bflo(k3.z) + qv[29]*bfhi(k3.z) + qv[30]*bflo(k3.w) + qv[31]*bfhi(k3.w);
            int ghm = m >> 3, gwm = m & 7;
            int ridx = (ghn - ghm + 7) * 15 + (gwn - gwm + 7);
            float sm = (d0 + d1 + d2 + d3) * rks[m][h] + reltab[h][ridx];

            float newM = fmaxf(M, sm);
            if (__any(newM > M)) {          // defer-rescale (wave-uniform)
                float corr = __expf(M - newM);
                L *= corr;
                #pragma unroll
                for (int j = 0; j < 32; ++j) ov[j] *= corr;
                M = newM;
            }
            float p = __expf(sm - M);
            L += p;
            uint4 v0 = *(const uint4*)(vb + m * HS + h * 32);
            uint4 v1 = *(const uint4*)(vb + m * HS + h * 32 + 8);
            uint4 v2 = *(const uint4*)(vb + m * HS + h * 32 + 16);
            uint4 v3 = *(const uint4*)(vb + m * HS + h * 32 + 24);
            ov[0] += p*bflo(v0.x); ov[1] += p*bfhi(v0.x); ov[2] += p*bflo(v0.y); ov[3] += p*bfhi(v0.y);
            ov[4] += p*bflo(v0.z); ov[5] += p*bfhi(v0.z); ov[6] += p*bflo(v0.w); ov[7] += p*bfhi(v0.w);
            ov[8] += p*bflo(v1.x); ov[9] += p*bfhi(v1.x); ov[10] += p*bflo(v1.y); ov[11] += p*bfhi(v1.y);
            ov[12] += p*bflo(v1.z); ov[13] += p*bfhi(v1.z); ov[14] += p*bflo(v1.w); ov[15] += p*bfhi(v1.w);
            ov[16] += p*bflo(v2.x); ov[17] += p*bfhi(v2.x); ov[18] += p*bflo(v2.y); ov[19] += p*bfhi(v2.y);
            ov[20] += p*bflo(v2.z); ov[21] += p*bfhi(v2.z); ov[22] += p*bflo(v2.w); ov[23] += p*bfhi(v2.w);
            ov[24] += p*bflo(v3.x); ov[25] += p*bfhi(v3.x); ov[26] += p*bflo(v3.y); ov[27] += p*bfhi(v3.y);
            ov[28] += p*bflo(v3.z); ov[29] += p*bfhi(v3.z); ov[30] += p*bflo(v3.w); ov[31] += p*bfhi(v3.w);
        }
        float inv = 1.f / L;
        unsigned short* obuf = hbuf;        // h is dead after P2
        #pragma unroll
        for (int j = 0; j < 32; ++j) obuf[n * HS + h * 32 + j] = f2bf(ov[j] * inv);
    }
    __syncthreads();

    // ---- P5: residual (re-gather x) + LN2 + scatter u (NCHW) ----
    const unsigned short* obuf = hbuf;
    for (int n = wv; n < 64; n += 8) {
        const int gh = n >> 3, gw = n & 7;
        const int hh = gh * 16 + hp, ww = gw * 16 + wp;
        const float* xp = x + ((size_t)(b * 256) * 128 + hh) * 128 + ww;
        float v0 = xp[(size_t)(lane) * 16384]        + bf2f(obuf[n * HS + lane]);
        float v1 = xp[(size_t)(lane + 64) * 16384]   + bf2f(obuf[n * HS + lane + 64]);
        float v2 = xp[(size_t)(lane + 128) * 16384]  + bf2f(obuf[n * HS + lane + 128]);
        float v3 = xp[(size_t)(lane + 192) * 16384]  + bf2f(obuf[n * HS + lane + 192]);
        float s = v0 + v1 + v2 + v3;
        float ss = v0 * v0 + v1 * v1 + v2 * v2 + v3 * v3;
        #pragma unroll
        for (int off = 32; off >= 1; off >>= 1) {
            s  += __shfl_xor(s, off);
            ss += __shfl_xor(ss, off);
        }
        float mean = s * (1.f / 256.f);
        float var  = ss * (1.f / 256.f) - mean * mean;
        float rstd = rsqrtf(var + 1e-5f);
        float vv[4] = {v0, v1, v2, v3};
        #pragma unroll
        for (int j = 0; j < 4; ++j) {
            int c = lane + j * 64;
            float u = (vv[j] - mean) * rstd * ln2g[c] + ln2b[c];
            uout[((size_t)(b * 256 + c) * 128 + hh) * 128 + ww] = u;
        }
    }
}

// ------------------------- conv3x3 + BN + GELU kernel ------------------------
// MODE 1: f32 src -> bf16 dst.  MODE 2: bf16 src -> f32 dst with residual add.
template <int MODE>
__global__ __launch_bounds__(256, 2) void conv_bn_gelu_kernel(
    const void* __restrict__ src_, const float* __restrict__ cw,
    const float* __restrict__ bng, const float* __restrict__ bnb,
    const float* __restrict__ bnm, const float* __restrict__ bnv,
    void* __restrict__ dst_, const float* __restrict__ resid)
{
    __shared__ float in_s[32][18][18];
    __shared__ float w_s[32][9][32];

    const int id = blockIdx.x;
    const int txl = id & 7, tyl = (id >> 3) & 7, oct = (id >> 6) & 7, b = id >> 9;
    const int h0 = tyl * 16, w0 = txl * 16;
    const int t = threadIdx.x;
    const int tx = t & 15, tyg = (t >> 4) & 3, ocg = t >> 6;

    float acc[4][8];
    #pragma unroll
    for (int j = 0; j < 4; ++j)
        #pragma unroll
        for (int p = 0; p < 8; ++p) acc[j][p] = 0.f;

    const float* srcf = (const float*)src_;
    const unsigned short* srcb = (const unsigned short*)src_;

    for (int cb = 0; cb < 8; ++cb) {
        for (int idx = t; idx < 10368; idx += 256) {
            int ci = idx / 324; int r = idx - ci * 324;
            int y = r / 18; int xx = r - y * 18;
            int gy = h0 + y - 1, gx = w0 + xx - 1;
            float val = 0.f;
            if (gy >= 0 && gy < 128 && gx >= 0 && gx < 128) {
                size_t gidx = ((size_t)(b * 256 + cb * 32 + ci) * 128 + gy) * 128 + gx;
                val = (MODE == 1) ? srcf[gidx] : bf2f(srcb[gidx]);
            }
            in_s[ci][y][xx] = val;
        }
        for (int idx = t; idx < 9216; idx += 256) {
            int oc = idx / 288; int r = idx - oc * 288;
            int ci = r / 9; int k = r - ci * 9;
            w_s[ci][k][oc] = cw[((size_t)(oct * 32 + oc) * 256 + cb * 32 + ci) * 9 + k];
        }
        __syncthreads();

        #pragma unroll 1
        for (int ci = 0; ci < 32; ++ci) {
            #pragma unroll
            for (int k = 0; k < 9; ++k) {
                const int ky = k / 3, kx = k - ky * 3;
                float4 wa = *(const float4*)&w_s[ci][k][ocg * 8];
                float4 wb = *(const float4*)&w_s[ci][k][ocg * 8 + 4];
                #pragma unroll
                for (int j = 0; j < 4; ++j) {
                    float iv = in_s[ci][tyg + 4 * j + ky][tx + kx];
                    acc[j][0] += iv * wa.x; acc[j][1] += iv * wa.y;
                    acc[j][2] += iv * wa.z; acc[j][3] += iv * wa.w;
                    acc[j][4] += iv * wb.x; acc[j][5] += iv * wb.y;
                    acc[j][6] += iv * wb.z; acc[j][7] += iv * wb.w;
                }
            }
        }
        __syncthreads();
    }

    #pragma unroll
    for (int p = 0; p < 8; ++p) {
        int oc = oct * 32 + ocg * 8 + p;
        float scl = bng[oc] * rsqrtf(bnv[oc] + 1e-5f);
        float sh  = bnb[oc] - bnm[oc] * scl;
        #pragma unroll
        for (int j = 0; j < 4; ++j) {
            int y = h0 + tyg + 4 * j, xx2 = w0 + tx;
            float v = acc[j][p] * scl + sh;
            float ge = 0.5f * v * (1.f + erff(v * 0.70710678118654752f));
            size_t gidx = ((size_t)(b * 256 + oc) * 128 + y) * 128 + xx2;
            if (MODE == 1) ((unsigned short*)dst_)[gidx] = f2bf(ge);
            else           ((float*)dst_)[gidx] = ge + resid[gidx];
        }
    }
}

// --------------------------------- launcher ----------------------------------
extern "C" void kernel_launch(void* const* d_in, const int* in_sizes, int n_in,
                              void* d_out, int out_size, void* d_ws, size_t ws_size,
                              hipStream_t stream)
{
    const float* x    = (const float*)d_in[0];
    const float* ln1g = (const float*)d_in[1];
    const float* ln1b = (const float*)d_in[2];
    const float* qkvw = (const float*)d_in[3];
    const float* relt = (const float*)d_in[4];
    const float* ln2g = (const float*)d_in[5];
    const float* ln2b = (const float*)d_in[6];
    const float* c1w  = (const float*)d_in[7];
    const float* bn1g = (const float*)d_in[8];
    const float* bn1b = (const float*)d_in[9];
    const float* bn1m = (const float*)d_in[10];
    const float* bn1v = (const float*)d_in[11];
    const float* c2w  = (const float*)d_in[12];
    const float* bn2g = (const float*)d_in[13];
    const float* bn2b = (const float*)d_in[14];
    const float* bn2m = (const float*)d_in[15];
    const float* bn2v = (const float*)d_in[16];

    float* out = (float*)d_out;
    unsigned short* wbf   = (unsigned short*)d_ws;                         // 393 KB
    unsigned short* hglob = (unsigned short*)((char*)d_ws + (512 << 10));  // 67 MB
    unsigned short* m1    = hglob;                                         // alias (h dead after attn)

    cvt_w_kernel<<<192, 256, 0, stream>>>(qkvw, wbf);
    gather_ln1_kernel<<<2048, 256, 0, stream>>>(x, ln1g, ln1b, hglob);
    attn2_kernel<<<2048, 512, 0, stream>>>(x, hglob, wbf, relt, ln2g, ln2b, out);
    conv_bn_gelu_kernel<1><<<4096, 256, 0, stream>>>(out, c1w, bn1g, bn1b, bn1m, bn1v,
                                                     (void*)m1, nullptr);
    conv_bn_gelu_kernel<2><<<4096, 256, 0, stream>>>((const void*)m1, c2w, bn2g, bn2b, bn2m, bn2v,
                                                     (void*)out, out);
}

// Round 4
// 1460.661 us; speedup vs baseline: 8.4192x; 4.7913x over previous
//
#include <hip/hip_runtime.h>

// Grid_Block: [B,C,H,W]=[8,256,128,128], window 8x8 (N=64), NH=8, hd=32.
// Fast path (ws >= 134 MiB):
//   K0 cvt_w(qkv), K0b/K0c wcvt(conv w -> [k][oc][ci] bf16)
//   K1 gather+LN1 -> h (NHWC bf16, ws)
//   K2 attn (MFMA QKV + per-head flash) -> u overwrites h in-place (NHWC bf16)
//   K3 convmm<1>: MFMA implicit-GEMM conv1+BN+GELU -> m1 (NHWC bf16, ws)
//   K4 convmm<2>: MFMA conv2+BN+GELU + u residual -> d_out (NCHW f32)
// Fallback (small ws): R3 pipeline (fp32 VALU convs via d_out staging).

#define DI __device__ __forceinline__
typedef __attribute__((ext_vector_type(8))) short bf16x8;
typedef __attribute__((ext_vector_type(4))) float f32x4;

DI unsigned short f2bf(float f) {
    unsigned u = __float_as_uint(f);
    u = u + 0x7FFFu + ((u >> 16) & 1u);   // RNE
    return (unsigned short)(u >> 16);
}
DI float bf2f(unsigned short s) { return __uint_as_float(((unsigned)s) << 16); }
DI float bflo(unsigned u) { return __uint_as_float(u << 16); }
DI float bfhi(unsigned u) { return __uint_as_float(u & 0xFFFF0000u); }

// ------------------------------- K0: qkv w -> bf16 ---------------------------
__global__ __launch_bounds__(256) void cvt_w_kernel(const float* __restrict__ w,
                                                    unsigned short* __restrict__ o) {
    int i = (blockIdx.x * 256 + threadIdx.x) * 4;   // grid 192 -> 196608 exact
    float4 f = *(const float4*)(w + i);
    ushort4 u;
    u.x = f2bf(f.x); u.y = f2bf(f.y); u.z = f2bf(f.z); u.w = f2bf(f.w);
    *(ushort4*)(o + i) = u;
}

// -------------------- K0b: conv w [oc][ci][3][3] -> [k][oc][ci] bf16 ---------
__global__ __launch_bounds__(256) void wcvt_kernel(const float* __restrict__ cw,
                                                   unsigned short* __restrict__ wt) {
    int t = blockIdx.x * 256 + threadIdx.x;   // 65536 = oc*256+ci
    int oc = t >> 8, ci = t & 255;
    const float* s = cw + (size_t)t * 9;
    #pragma unroll
    for (int k = 0; k < 9; ++k)
        wt[((size_t)k * 256 + oc) * 256 + ci] = f2bf(s[k]);
}

// --------------------- K1: gather + LN1 -> h (NHWC bf16) ---------------------
__global__ __launch_bounds__(256) void gather_ln1_kernel(
    const float* __restrict__ x, const float* __restrict__ g1, const float* __restrict__ b1,
    unsigned short* __restrict__ hu)
{
    const int win = blockIdx.x;
    const int b = win >> 8, hp = (win >> 4) & 15, wp = win & 15;
    const int t = threadIdx.x, lane = t & 63, wv = t >> 6;

    for (int n = wv; n < 64; n += 4) {
        const int gh = n >> 3, gw = n & 7;
        const int hh = gh * 16 + hp, ww = gw * 16 + wp;
        const float* xp = x + ((size_t)(b * 256) * 128 + hh) * 128 + ww;
        float v0 = xp[(size_t)(lane) * 16384];
        float v1 = xp[(size_t)(lane + 64) * 16384];
        float v2 = xp[(size_t)(lane + 128) * 16384];
        float v3 = xp[(size_t)(lane + 192) * 16384];
        float s = v0 + v1 + v2 + v3;
        float ss = v0 * v0 + v1 * v1 + v2 * v2 + v3 * v3;
        #pragma unroll
        for (int off = 32; off >= 1; off >>= 1) {
            s  += __shfl_xor(s, off);
            ss += __shfl_xor(ss, off);
        }
        float mean = s * (1.f / 256.f);
        float var  = ss * (1.f / 256.f) - mean * mean;
        float rstd = rsqrtf(var + 1e-5f);
        size_t pix = ((size_t)(b * 128 + hh) << 7) + ww;
        unsigned short* hrow = hu + pix * 256;
        float vv[4] = {v0, v1, v2, v3};
        #pragma unroll
        for (int j = 0; j < 4; ++j) {
            int c = lane + j * 64;
            hrow[c] = f2bf((vv[j] - mean) * rstd * g1[c] + b1[c]);
        }
    }
}

// ------------------------------ K2: attention --------------------------------
// UMODE 0: write u as NCHW f32 to uout (fallback). UMODE 1: overwrite hu rows
// in-place with u (NHWC bf16) — rows are window-exclusive, so race-free.
#define HS 264   // ushort row stride: 528 B
template <int UMODE>
__global__ __launch_bounds__(512, 1) void attn2_kernel(
    const float* __restrict__ x, unsigned short* __restrict__ hu,
    const unsigned short* __restrict__ wbf, const float* __restrict__ relt,
    const float* __restrict__ ln2g, const float* __restrict__ ln2b,
    float* __restrict__ uout)
{
    __shared__ unsigned short hbuf[64 * HS];   // h tile; reused as o (bf16)
    __shared__ unsigned short qb[64 * HS];
    __shared__ unsigned short kb[64 * HS];
    __shared__ unsigned short vb[64 * HS];
    __shared__ float reltab[8][232];
    __shared__ float rqs[64][8], rks[64][8];

    const int win = blockIdx.x;
    const int b = win >> 8, hp = (win >> 4) & 15, wp = win & 15;
    const int t = threadIdx.x, lane = t & 63, wv = t >> 6;   // 8 waves
    const int l15 = lane & 15, l4 = lane >> 4;

    // ---- P1: h-tile load (NHWC rows of this window) + rel-table transpose ----
    for (int i = t; i < 2048; i += 512) {
        int row = i >> 5, col8 = (i & 31) * 8;
        int gy = (row >> 3) * 16 + hp, gx = (row & 7) * 16 + wp;
        size_t pix = ((size_t)(b * 128 + gy) << 7) + gx;
        uint4 val = *(const uint4*)(hu + pix * 256 + col8);
        *(uint4*)(hbuf + row * HS + col8) = val;
    }
    for (int i = t; i < 1800; i += 512) reltab[i & 7][i >> 3] = relt[i];
    __syncthreads();

    // ---- P2: QKV GEMM via MFMA (M=64, N=768, K=256) ----
    {
        f32x4 acc[4][6];
        #pragma unroll
        for (int mt = 0; mt < 4; ++mt)
            #pragma unroll
            for (int nt = 0; nt < 6; ++nt) acc[mt][nt] = (f32x4){0.f, 0.f, 0.f, 0.f};
        const int ntb = wv * 6;
        for (int kk = 0; kk < 8; ++kk) {
            bf16x8 afr[4];
            #pragma unroll
            for (int mt = 0; mt < 4; ++mt)
                afr[mt] = *(const bf16x8*)(hbuf + (mt * 16 + l15) * HS + kk * 32 + l4 * 8);
            #pragma unroll
            for (int nt = 0; nt < 6; ++nt) {
                int d = (ntb + nt) * 16 + l15;
                bf16x8 bfr = *(const bf16x8*)(wbf + d * 256 + kk * 32 + l4 * 8);
                #pragma unroll
                for (int mt = 0; mt < 4; ++mt)
                    acc[mt][nt] = __builtin_amdgcn_mfma_f32_16x16x32_bf16(afr[mt], bfr, acc[mt][nt], 0, 0, 0);
            }
        }
        #pragma unroll
        for (int nt = 0; nt < 6; ++nt) {
            int d = (ntb + nt) * 16 + l15;
            unsigned short* dst = (d < 256) ? qb : (d < 512 ? kb : vb);
            int dd = d & 255;
            #pragma unroll
            for (int mt = 0; mt < 4; ++mt)
                #pragma unroll
                for (int r = 0; r < 4; ++r) {
                    int n = mt * 16 + l4 * 4 + r;
                    dst[n * HS + dd] = f2bf(acc[mt][nt][r]);
                }
        }
    }
    __syncthreads();

    // ---- P3: cosine-norm factors ----
    {
        const int n = t & 63, hh = t >> 6;
        float sq = 0.f, sk = 0.f;
        #pragma unroll
        for (int j = 0; j < 32; j += 2) {
            unsigned uq = *(const unsigned*)(qb + n * HS + hh * 32 + j);
            unsigned uk = *(const unsigned*)(kb + n * HS + hh * 32 + j);
            float q0 = bflo(uq), q1 = bfhi(uq), k0 = bflo(uk), k1 = bfhi(uk);
            sq += q0 * q0 + q1 * q1;
            sk += k0 * k0 + k1 * k1;
        }
        rqs[n][hh] = rsqrtf(sq);
        rks[n][hh] = rsqrtf(sk);
    }
    __syncthreads();

    // ---- P4: per-head flash attention (wave = head, lane = query row) ----
    {
        const int h = wv, n = lane;
        const int ghn = n >> 3, gwn = n & 7;
        float qv[32];
        #pragma unroll
        for (int j = 0; j < 32; j += 2) {
            unsigned uq = *(const unsigned*)(qb + n * HS + h * 32 + j);
            qv[j] = bflo(uq); qv[j + 1] = bfhi(uq);
        }
        float qscale = rqs[n][h] * 0.17677669529663687f;
        #pragma unroll
        for (int j = 0; j < 32; ++j) qv[j] *= qscale;

        float M = -3.0e38f, L = 0.f;
        float ov[32];
        #pragma unroll
        for (int j = 0; j < 32; ++j) ov[j] = 0.f;

        #pragma unroll 4
        for (int m = 0; m < 64; ++m) {
            uint4 k0 = *(const uint4*)(kb + m * HS + h * 32);
            uint4 k1 = *(const uint4*)(kb + m * HS + h * 32 + 8);
            uint4 k2 = *(const uint4*)(kb + m * HS + h * 32 + 16);
            uint4 k3 = *(const uint4*)(kb + m * HS + h * 32 + 24);
            float d0 = 0.f, d1 = 0.f, d2 = 0.f, d3 = 0.f;
            d0 += qv[0]*bflo(k0.x) + qv[1]*bfhi(k0.x) + qv[2]*bflo(k0.y) + qv[3]*bfhi(k0.y);
            d1 += qv[4]*bflo(k0.z) + qv[5]*bfhi(k0.z) + qv[6]*bflo(k0.w) + qv[7]*bfhi(k0.w);
            d2 += qv[8]*bflo(k1.x) + qv[9]*bfhi(k1.x) + qv[10]*bflo(k1.y) + qv[11]*bfhi(k1.y);
            d3 += qv[12]*bflo(k1.z) + qv[13]*bfhi(k1.z) + qv[14]*bflo(k1.w) + qv[15]*bfhi(k1.w);
            d0 += qv[16]*bflo(k2.x) + qv[17]*bfhi(k2.x) + qv[18]*bflo(k2.y) + qv[19]*bfhi(k2.y);
            d1 += qv[20]*bflo(k2.z) + qv[21]*bfhi(k2.z) + qv[22]*bflo(k2.w) + qv[23]*bfhi(k2.w);
            d2 += qv[24]*bflo(k3.x) + qv[25]*bfhi(k3.x) + qv[26]*bflo(k3.y) + qv[27]*bfhi(k3.y);
            d3 += qv[28]*bflo(k3.z) + qv[29]*bfhi(k3.z) + qv[30]*bflo(k3.w) + qv[31]*bfhi(k3.w);
            int ghm = m >> 3, gwm = m & 7;
            int ridx = (ghn - ghm + 7) * 15 + (gwn - gwm + 7);
            float sm = (d0 + d1 + d2 + d3) * rks[m][h] + reltab[h][ridx];

            float newM = fmaxf(M, sm);
            if (__any(newM > M)) {
                float corr = __expf(M - newM);
                L *= corr;
                #pragma unroll
                for (int j = 0; j < 32; ++j) ov[j] *= corr;
                M = newM;
            }
            float p = __expf(sm - M);
            L += p;
            uint4 v0 = *(const uint4*)(vb + m * HS + h * 32);
            uint4 v1 = *(const uint4*)(vb + m * HS + h * 32 + 8);
            uint4 v2 = *(const uint4*)(vb + m * HS + h * 32 + 16);
            uint4 v3 = *(const uint4*)(vb + m * HS + h * 32 + 24);
            ov[0] += p*bflo(v0.x); ov[1] += p*bfhi(v0.x); ov[2] += p*bflo(v0.y); ov[3] += p*bfhi(v0.y);
            ov[4] += p*bflo(v0.z); ov[5] += p*bfhi(v0.z); ov[6] += p*bflo(v0.w); ov[7] += p*bfhi(v0.w);
            ov[8] += p*bflo(v1.x); ov[9] += p*bfhi(v1.x); ov[10] += p*bflo(v1.y); ov[11] += p*bfhi(v1.y);
            ov[12] += p*bflo(v1.z); ov[13] += p*bfhi(v1.z); ov[14] += p*bflo(v1.w); ov[15] += p*bfhi(v1.w);
            ov[16] += p*bflo(v2.x); ov[17] += p*bfhi(v2.x); ov[18] += p*bflo(v2.y); ov[19] += p*bfhi(v2.y);
            ov[20] += p*bflo(v2.z); ov[21] += p*bfhi(v2.z); ov[22] += p*bflo(v2.w); ov[23] += p*bfhi(v2.w);
            ov[24] += p*bflo(v3.x); ov[25] += p*bfhi(v3.x); ov[26] += p*bflo(v3.y); ov[27] += p*bfhi(v3.y);
            ov[28] += p*bflo(v3.z); ov[29] += p*bfhi(v3.z); ov[30] += p*bflo(v3.w); ov[31] += p*bfhi(v3.w);
        }
        float inv = 1.f / L;
        #pragma unroll
        for (int j = 0; j < 32; ++j) hbuf[n * HS + h * 32 + j] = f2bf(ov[j] * inv);
    }
    __syncthreads();

    // ---- P5: residual (re-gather x) + LN2 -> u ----
    for (int n = wv; n < 64; n += 8) {
        const int gh = n >> 3, gw = n & 7;
        const int hh = gh * 16 + hp, ww = gw * 16 + wp;
        const float* xp = x + ((size_t)(b * 256) * 128 + hh) * 128 + ww;
        float v0 = xp[(size_t)(lane) * 16384]        + bf2f(hbuf[n * HS + lane]);
        float v1 = xp[(size_t)(lane + 64) * 16384]   + bf2f(hbuf[n * HS + lane + 64]);
        float v2 = xp[(size_t)(lane + 128) * 16384]  + bf2f(hbuf[n * HS + lane + 128]);
        float v3 = xp[(size_t)(lane + 192) * 16384]  + bf2f(hbuf[n * HS + lane + 192]);
        float s = v0 + v1 + v2 + v3;
        float ss = v0 * v0 + v1 * v1 + v2 * v2 + v3 * v3;
        #pragma unroll
        for (int off = 32; off >= 1; off >>= 1) {
            s  += __shfl_xor(s, off);
            ss += __shfl_xor(ss, off);
        }
        float mean = s * (1.f / 256.f);
        float var  = ss * (1.f / 256.f) - mean * mean;
        float rstd = rsqrtf(var + 1e-5f);
        float vv[4] = {v0, v1, v2, v3};
        size_t pix = ((size_t)(b * 128 + hh) << 7) + ww;
        #pragma unroll
        for (int j = 0; j < 4; ++j) {
            int c = lane + j * 64;
            float u = (vv[j] - mean) * rstd * ln2g[c] + ln2b[c];
            if (UMODE == 0)
                uout[((size_t)(b * 256 + c) * 128 + hh) * 128 + ww] = u;
            else
                hu[pix * 256 + c] = f2bf(u);
        }
    }
}

// ---------------- K3/K4: MFMA implicit-GEMM conv3x3 + BN + GELU --------------
// Tile: 16w x 8h output pixels, full 256 oc. Input NHWC bf16 halo 18x10 in LDS
// (XOR-swizzled). Weights [k][oc][ci] bf16 streamed from L2. 8 waves: wave wv
// owns oc [wv*32, wv*32+32) x all 128 px. No barriers in the K-loop.
// MODE 1: dst = m1 NHWC bf16. MODE 2: dst = out NCHW f32 + residual (NHWC bf16).
template <int MODE>
__global__ __launch_bounds__(512, 1) void convmm_kernel(
    const unsigned short* __restrict__ src, const unsigned short* __restrict__ wt,
    const float* __restrict__ bng, const float* __restrict__ bnb,
    const float* __restrict__ bnm, const float* __restrict__ bnv,
    unsigned short* __restrict__ dstb, float* __restrict__ dstf,
    const unsigned short* __restrict__ ubuf)
{
    __shared__ unsigned short in_s[180 * 256];   // 92160 B, swizzled
    __shared__ float scl_s[256], sh_s[256];

    const int id = blockIdx.x;
    const int bx = id & 7, by = (id >> 3) & 15, b = id >> 7;
    const int x0 = bx * 16, y0 = by * 8;
    const int t = threadIdx.x, lane = t & 63, wv = t >> 6;
    const int l15 = lane & 15, l4 = lane >> 4;

    if (t < 256) {
        float iv = rsqrtf(bnv[t] + 1e-5f) * bng[t];
        scl_s[t] = iv;
        sh_s[t] = bnb[t] - bnm[t] * iv;
    }

    // ---- stage input halo (zero-padded), swizzle: byte ^= (ip&7)<<4 ----
    const char* in_s_base = (const char*)in_s;
    for (int i = t; i < 5760; i += 512) {
        int ip = i >> 5, ch = i & 31;
        int iy = ip / 18, ix = ip - iy * 18;
        int gy = y0 + iy - 1, gx = x0 + ix - 1;
        uint4 v = {0u, 0u, 0u, 0u};
        if ((unsigned)gy < 128u && (unsigned)gx < 128u)
            v = *(const uint4*)(src + (((size_t)(b * 128 + gy) << 7) + gx) * 256 + ch * 8);
        *(uint4*)((char*)in_s + ip * 512 + ((ch * 16) ^ ((ip & 7) << 4))) = v;
    }
    __syncthreads();

    f32x4 acc[2][8];
    #pragma unroll
    for (int o = 0; o < 2; ++o)
        #pragma unroll
        for (int p = 0; p < 8; ++p) acc[o][p] = (f32x4){0.f, 0.f, 0.f, 0.f};

    for (int cic = 0; cic < 8; ++cic) {
        #pragma unroll
        for (int ky = 0; ky < 3; ++ky) {
            #pragma unroll
            for (int kx = 0; kx < 3; ++kx) {
                const unsigned short* wp_ = wt + ((size_t)((ky * 3 + kx) * 256 + (wv << 5) + l15)) * 256
                                               + cic * 32 + l4 * 8;
                bf16x8 wf0 = *(const bf16x8*)(wp_);
                bf16x8 wf1 = *(const bf16x8*)(wp_ + 16 * 256);
                const int cbyte = cic * 64 + l4 * 16;
                #pragma unroll
                for (int pxt = 0; pxt < 8; ++pxt) {
                    int ip = (pxt + ky) * 18 + l15 + kx;
                    bf16x8 bf = *(const bf16x8*)(in_s_base + ip * 512 + (cbyte ^ ((ip & 7) << 4)));
                    acc[0][pxt] = __builtin_amdgcn_mfma_f32_16x16x32_bf16(wf0, bf, acc[0][pxt], 0, 0, 0);
                    acc[1][pxt] = __builtin_amdgcn_mfma_f32_16x16x32_bf16(wf1, bf, acc[1][pxt], 0, 0, 0);
                }
            }
        }
    }

    // ---- epilogue: BN + GELU (+ residual, store) ----
    // C layout: row(oc_local) = l4*4 + r, col(pixel) = l15
    #pragma unroll
    for (int oct = 0; oct < 2; ++oct) {
        const int ocb = (wv << 5) + oct * 16 + (l4 << 2);
        float scl[4], sh[4];
        #pragma unroll
        for (int r = 0; r < 4; ++r) { scl[r] = scl_s[ocb + r]; sh[r] = sh_s[ocb + r]; }
        #pragma unroll
        for (int pxt = 0; pxt < 8; ++pxt) {
            const int gy = y0 + pxt, gx = x0 + l15;
            const size_t pix = ((size_t)(b * 128 + gy) << 7) + gx;
            if (MODE == 1) {
                unsigned pk0, pk1;
                float v0 = acc[oct][pxt][0] * scl[0] + sh[0];
                float v1 = acc[oct][pxt][1] * scl[1] + sh[1];
                float v2 = acc[oct][pxt][2] * scl[2] + sh[2];
                float v3 = acc[oct][pxt][3] * scl[3] + sh[3];
                float g0 = 0.5f * v0 * (1.f + erff(v0 * 0.70710678118654752f));
                float g1 = 0.5f * v1 * (1.f + erff(v1 * 0.70710678118654752f));
                float g2 = 0.5f * v2 * (1.f + erff(v2 * 0.70710678118654752f));
                float g3 = 0.5f * v3 * (1.f + erff(v3 * 0.70710678118654752f));
                pk0 = (unsigned)f2bf(g0) | ((unsigned)f2bf(g1) << 16);
                pk1 = (unsigned)f2bf(g2) | ((unsigned)f2bf(g3) << 16);
                uint2 pk; pk.x = pk0; pk.y = pk1;
                *(uint2*)(dstb + pix * 256 + ocb) = pk;
            } else {
                uint2 ur = *(const uint2*)(ubuf + pix * 256 + ocb);
                float res[4] = {bflo(ur.x), bfhi(ur.x), bflo(ur.y), bfhi(ur.y)};
                #pragma unroll
                for (int r = 0; r < 4; ++r) {
                    float v = acc[oct][pxt][r] * scl[r] + sh[r];
                    float ge = 0.5f * v * (1.f + erff(v * 0.70710678118654752f));
                    dstf[(((size_t)(b * 256 + ocb + r)) << 14) + (gy << 7) + gx] = ge + res[r];
                }
            }
        }
    }
}

// ------------------- fallback conv (R3, fp32 VALU direct) --------------------
template <int MODE>
__global__ __launch_bounds__(256, 2) void conv_bn_gelu_kernel(
    const void* __restrict__ src_, const float* __restrict__ cw,
    const float* __restrict__ bng, const float* __restrict__ bnb,
    const float* __restrict__ bnm, const float* __restrict__ bnv,
    void* __restrict__ dst_, const float* __restrict__ resid)
{
    __shared__ float in_s[32][18][18];
    __shared__ float w_s[32][9][32];

    const int id = blockIdx.x;
    const int txl = id & 7, tyl = (id >> 3) & 7, oct = (id >> 6) & 7, b = id >> 9;
    const int h0 = tyl * 16, w0 = txl * 16;
    const int t = threadIdx.x;
    const int tx = t & 15, tyg = (t >> 4) & 3, ocg = t >> 6;

    float acc[4][8];
    #pragma unroll
    for (int j = 0; j < 4; ++j)
        #pragma unroll
        for (int p = 0; p < 8; ++p) acc[j][p] = 0.f;

    const float* srcf = (const float*)src_;
    const unsigned short* srcb = (const unsigned short*)src_;

    for (int cb = 0; cb < 8; ++cb) {
        for (int idx = t; idx < 10368; idx += 256) {
            int ci = idx / 324; int r = idx - ci * 324;
            int y = r / 18; int xx = r - y * 18;
            int gy = h0 + y - 1, gx = w0 + xx - 1;
            float val = 0.f;
            if (gy >= 0 && gy < 128 && gx >= 0 && gx < 128) {
                size_t gidx = ((size_t)(b * 256 + cb * 32 + ci) * 128 + gy) * 128 + gx;
                val = (MODE == 1) ? srcf[gidx] : bf2f(srcb[gidx]);
            }
            in_s[ci][y][xx] = val;
        }
        for (int idx = t; idx < 9216; idx += 256) {
            int oc = idx / 288; int r = idx - oc * 288;
            int ci = r / 9; int k = r - ci * 9;
            w_s[ci][k][oc] = cw[((size_t)(oct * 32 + oc) * 256 + cb * 32 + ci) * 9 + k];
        }
        __syncthreads();

        #pragma unroll 1
        for (int ci = 0; ci < 32; ++ci) {
            #pragma unroll
            for (int k = 0; k < 9; ++k) {
                const int ky = k / 3, kx = k - ky * 3;
                float4 wa = *(const float4*)&w_s[ci][k][ocg * 8];
                float4 wb = *(const float4*)&w_s[ci][k][ocg * 8 + 4];
                #pragma unroll
                for (int j = 0; j < 4; ++j) {
                    float iv = in_s[ci][tyg + 4 * j + ky][tx + kx];
                    acc[j][0] += iv * wa.x; acc[j][1] += iv * wa.y;
                    acc[j][2] += iv * wa.z; acc[j][3] += iv * wa.w;
                    acc[j][4] += iv * wb.x; acc[j][5] += iv * wb.y;
                    acc[j][6] += iv * wb.z; acc[j][7] += iv * wb.w;
                }
            }
        }
        __syncthreads();
    }

    #pragma unroll
    for (int p = 0; p < 8; ++p) {
        int oc = oct * 32 + ocg * 8 + p;
        float scl = bng[oc] * rsqrtf(bnv[oc] + 1e-5f);
        float sh  = bnb[oc] - bnm[oc] * scl;
        #pragma unroll
        for (int j = 0; j < 4; ++j) {
            int y = h0 + tyg + 4 * j, xx2 = w0 + tx;
            float v = acc[j][p] * scl + sh;
            float ge = 0.5f * v * (1.f + erff(v * 0.70710678118654752f));
            size_t gidx = ((size_t)(b * 256 + oc) * 128 + y) * 128 + xx2;
            if (MODE == 1) ((unsigned short*)dst_)[gidx] = f2bf(ge);
            else           ((float*)dst_)[gidx] = ge + resid[gidx];
        }
    }
}

// --------------------------------- launcher ----------------------------------
extern "C" void kernel_launch(void* const* d_in, const int* in_sizes, int n_in,
                              void* d_out, int out_size, void* d_ws, size_t ws_size,
                              hipStream_t stream)
{
    const float* x    = (const float*)d_in[0];
    const float* ln1g = (const float*)d_in[1];
    const float* ln1b = (const float*)d_in[2];
    const float* qkvw = (const float*)d_in[3];
    const float* relt = (const float*)d_in[4];
    const float* ln2g = (const float*)d_in[5];
    const float* ln2b = (const float*)d_in[6];
    const float* c1w  = (const float*)d_in[7];
    const float* bn1g = (const float*)d_in[8];
    const float* bn1b = (const float*)d_in[9];
    const float* bn1m = (const float*)d_in[10];
    const float* bn1v = (const float*)d_in[11];
    const float* c2w  = (const float*)d_in[12];
    const float* bn2g = (const float*)d_in[13];
    const float* bn2b = (const float*)d_in[14];
    const float* bn2m = (const float*)d_in[15];
    const float* bn2v = (const float*)d_in[16];

    float* out = (float*)d_out;
    char* ws = (char*)d_ws;

    if (ws_size >= ((size_t)134 << 20)) {
        // ---------------- fast path (MFMA convs) ----------------
        unsigned short* wbf = (unsigned short*)ws;                      // 384 KB
        unsigned short* wt1 = (unsigned short*)(ws + ((size_t)1 << 20)); // 1.13 MB
        unsigned short* wt2 = (unsigned short*)(ws + ((size_t)3 << 20)); // 1.13 MB
        unsigned short* hu  = (unsigned short*)(ws + ((size_t)5 << 20)); // 64 MiB
        unsigned short* m1  = (unsigned short*)(ws + ((size_t)69 << 20)); // 64 MiB

        cvt_w_kernel<<<192, 256, 0, stream>>>(qkvw, wbf);
        wcvt_kernel<<<256, 256, 0, stream>>>(c1w, wt1);
        wcvt_kernel<<<256, 256, 0, stream>>>(c2w, wt2);
        gather_ln1_kernel<<<2048, 256, 0, stream>>>(x, ln1g, ln1b, hu);
        attn2_kernel<1><<<2048, 512, 0, stream>>>(x, hu, wbf, relt, ln2g, ln2b, nullptr);
        convmm_kernel<1><<<1024, 512, 0, stream>>>(hu, wt1, bn1g, bn1b, bn1m, bn1v,
                                                   m1, nullptr, nullptr);
        convmm_kernel<2><<<1024, 512, 0, stream>>>(m1, wt2, bn2g, bn2b, bn2m, bn2v,
                                                   nullptr, out, hu);
    } else {
        // ---------------- fallback (R3 pipeline) ----------------
        unsigned short* wbf = (unsigned short*)ws;
        unsigned short* hu  = (unsigned short*)(ws + (512 << 10));
        unsigned short* m1  = hu;   // alias: h dead after attn

        cvt_w_kernel<<<192, 256, 0, stream>>>(qkvw, wbf);
        gather_ln1_kernel<<<2048, 256, 0, stream>>>(x, ln1g, ln1b, hu);
        attn2_kernel<0><<<2048, 512, 0, stream>>>(x, hu, wbf, relt, ln2g, ln2b, out);
        conv_bn_gelu_kernel<1><<<4096, 256, 0, stream>>>(out, c1w, bn1g, bn1b, bn1m, bn1v,
                                                         (void*)m1, nullptr);
        conv_bn_gelu_kernel<2><<<4096, 256, 0, stream>>>((const void*)m1, c2w, bn2g, bn2b, bn2m, bn2v,
                                                         (void*)out, out);
    }
}

// Round 5
// 1053.788 us; speedup vs baseline: 11.6698x; 1.3861x over previous
//
#include <hip/hip_runtime.h>

// Grid_Block: [B,C,H,W]=[8,256,128,128], window 8x8 (N=64), NH=8, hd=32.
// Fast path (ws >= 134 MiB):
//   K0 cvt_w(qkv), K0b/K0c wcvt(conv w -> [k][oc][ci] bf16)
//   K1 gather+LN1 -> h (NHWC bf16) + g residual (NHWC bf16, m1 slot)
//   K2 attn: MFMA QKV + MFMA QK^T/softmax/PV per head-wave + LN2 -> u in-place (NHWC bf16)
//   K3 convmm<1>: MFMA implicit-GEMM conv1+BN+GELU -> m1 (NHWC bf16, overwrites g)
//   K4 convmm<2>: MFMA conv2+BN+GELU + u residual -> d_out (NCHW f32)
// Fallback (small ws): MFMA attn with x-regather + fp32 VALU convs.

#define DI __device__ __forceinline__
typedef __attribute__((ext_vector_type(8))) short bf16x8;
typedef __attribute__((ext_vector_type(4))) float f32x4;

DI unsigned short f2bf(float f) {
    unsigned u = __float_as_uint(f);
    u = u + 0x7FFFu + ((u >> 16) & 1u);   // RNE
    return (unsigned short)(u >> 16);
}
DI float bf2f(unsigned short s) { return __uint_as_float(((unsigned)s) << 16); }
DI float bflo(unsigned u) { return __uint_as_float(u << 16); }
DI float bfhi(unsigned u) { return __uint_as_float(u & 0xFFFF0000u); }

// ------------------------------- K0: qkv w -> bf16 ---------------------------
__global__ __launch_bounds__(256) void cvt_w_kernel(const float* __restrict__ w,
                                                    unsigned short* __restrict__ o) {
    int i = (blockIdx.x * 256 + threadIdx.x) * 4;
    float4 f = *(const float4*)(w + i);
    ushort4 u;
    u.x = f2bf(f.x); u.y = f2bf(f.y); u.z = f2bf(f.z); u.w = f2bf(f.w);
    *(ushort4*)(o + i) = u;
}

// -------------------- K0b: conv w [oc][ci][3][3] -> [k][oc][ci] bf16 ---------
__global__ __launch_bounds__(256) void wcvt_kernel(const float* __restrict__ cw,
                                                   unsigned short* __restrict__ wt) {
    int t = blockIdx.x * 256 + threadIdx.x;   // 65536 = oc*256+ci
    int oc = t >> 8, ci = t & 255;
    const float* s = cw + (size_t)t * 9;
    #pragma unroll
    for (int k = 0; k < 9; ++k)
        wt[((size_t)k * 256 + oc) * 256 + ci] = f2bf(s[k]);
}

// --------- K1: gather + LN1 -> h (NHWC bf16); also g residual (bf16) ---------
template <int GSTORE>
__global__ __launch_bounds__(256) void gather_ln1_kernel(
    const float* __restrict__ x, const float* __restrict__ g1, const float* __restrict__ b1,
    unsigned short* __restrict__ hu, unsigned short* __restrict__ gbuf)
{
    const int win = blockIdx.x;
    const int b = win >> 8, hp = (win >> 4) & 15, wp = win & 15;
    const int t = threadIdx.x, lane = t & 63, wv = t >> 6;

    for (int n = wv; n < 64; n += 4) {
        const int gh = n >> 3, gw = n & 7;
        const int hh = gh * 16 + hp, ww = gw * 16 + wp;
        const float* xp = x + ((size_t)(b * 256) * 128 + hh) * 128 + ww;
        float v0 = xp[(size_t)(lane) * 16384];
        float v1 = xp[(size_t)(lane + 64) * 16384];
        float v2 = xp[(size_t)(lane + 128) * 16384];
        float v3 = xp[(size_t)(lane + 192) * 16384];
        float s = v0 + v1 + v2 + v3;
        float ss = v0 * v0 + v1 * v1 + v2 * v2 + v3 * v3;
        #pragma unroll
        for (int off = 32; off >= 1; off >>= 1) {
            s  += __shfl_xor(s, off);
            ss += __shfl_xor(ss, off);
        }
        float mean = s * (1.f / 256.f);
        float var  = ss * (1.f / 256.f) - mean * mean;
        float rstd = rsqrtf(var + 1e-5f);
        size_t pix = ((size_t)(b * 128 + hh) << 7) + ww;
        unsigned short* hrow = hu + pix * 256;
        unsigned short* grow = GSTORE ? (gbuf + pix * 256) : nullptr;
        float vv[4] = {v0, v1, v2, v3};
        #pragma unroll
        for (int j = 0; j < 4; ++j) {
            int c = lane + j * 64;
            hrow[c] = f2bf((vv[j] - mean) * rstd * g1[c] + b1[c]);
            if (GSTORE) grow[c] = f2bf(vv[j]);
        }
    }
}

// ------------------------------ K2: attention --------------------------------
// UMODE 0: P5 re-gathers x, writes u NCHW f32 (fallback).
// UMODE 1: P5 reads g (NHWC bf16), overwrites hu in-place with u (NHWC bf16).
#define HS 264   // ushort row stride (528 B, 16B-aligned, 132 dw -> 2-way on 16-row frags)
#define VS 72    // vbT ushort row stride (144 B)
template <int UMODE>
__global__ __launch_bounds__(512, 1) void attn2_kernel(
    const float* __restrict__ x, unsigned short* __restrict__ hu,
    const unsigned short* __restrict__ gbuf,
    const unsigned short* __restrict__ wbf, const float* __restrict__ relt,
    const float* __restrict__ ln2g, const float* __restrict__ ln2b,
    float* __restrict__ uout)
{
    __shared__ unsigned short hbuf[64 * HS];    // h tile; reused as o (bf16)
    __shared__ unsigned short qb[64 * HS];      // q; halves reused for P[m<32]
    __shared__ unsigned short kb[64 * HS];      // k; halves reused for P[m>=32]
    __shared__ unsigned short vbT[256 * VS];    // v transposed [d][m]
    __shared__ float reltab[8][232];

    const int win = blockIdx.x;
    const int b = win >> 8, hp = (win >> 4) & 15, wp = win & 15;
    const int t = threadIdx.x, lane = t & 63, wv = t >> 6;   // 8 waves
    const int l15 = lane & 15, l4 = lane >> 4;

    // ---- P1: h-tile load (coalesced NHWC window rows) + rel-table transpose ----
    for (int i = t; i < 2048; i += 512) {
        int row = i >> 5, col8 = (i & 31) * 8;
        int gy = (row >> 3) * 16 + hp, gx = (row & 7) * 16 + wp;
        size_t pix = ((size_t)(b * 128 + gy) << 7) + gx;
        uint4 val = *(const uint4*)(hu + pix * 256 + col8);
        *(uint4*)(hbuf + row * HS + col8) = val;
    }
    for (int i = t; i < 1800; i += 512) reltab[i & 7][i >> 3] = relt[i];
    __syncthreads();

    // ---- P2: QKV GEMM via MFMA (M=64, N=768, K=256); wave owns 6 N-tiles ----
    {
        f32x4 acc[4][6];
        #pragma unroll
        for (int mt = 0; mt < 4; ++mt)
            #pragma unroll
            for (int nt = 0; nt < 6; ++nt) acc[mt][nt] = (f32x4){0.f, 0.f, 0.f, 0.f};
        const int ntb = wv * 6;
        for (int kk = 0; kk < 8; ++kk) {
            bf16x8 afr[4];
            #pragma unroll
            for (int mt = 0; mt < 4; ++mt)
                afr[mt] = *(const bf16x8*)(hbuf + (mt * 16 + l15) * HS + kk * 32 + l4 * 8);
            #pragma unroll
            for (int nt = 0; nt < 6; ++nt) {
                int d = (ntb + nt) * 16 + l15;
                bf16x8 bfr = *(const bf16x8*)(wbf + d * 256 + kk * 32 + l4 * 8);
                #pragma unroll
                for (int mt = 0; mt < 4; ++mt)
                    acc[mt][nt] = __builtin_amdgcn_mfma_f32_16x16x32_bf16(afr[mt], bfr, acc[mt][nt], 0, 0, 0);
            }
        }
        // scatter: q,k -> [n][d] rows; v -> transposed [d][n]
        #pragma unroll
        for (int nt = 0; nt < 6; ++nt) {
            int seg = ntb + nt;               // 0..47 (wave-uniform)
            int d = seg * 16 + l15;
            int dd = d & 255;
            if (seg < 32) {
                unsigned short* dst = (seg < 16) ? qb : kb;
                #pragma unroll
                for (int mt = 0; mt < 4; ++mt)
                    #pragma unroll
                    for (int r = 0; r < 4; ++r) {
                        int n = mt * 16 + l4 * 4 + r;
                        dst[n * HS + dd] = f2bf(acc[mt][nt][r]);
                    }
            } else {
                #pragma unroll
                for (int mt = 0; mt < 4; ++mt)
                    #pragma unroll
                    for (int r = 0; r < 4; ++r) {
                        int n = mt * 16 + l4 * 4 + r;
                        vbT[dd * VS + n] = f2bf(acc[mt][nt][r]);
                    }
            }
        }
    }
    __syncthreads();

    // ---- P3 (wave-local, no barrier needed): cosine-normalize q,k of head wv ----
    {
        const int h = wv, n = lane;
        unsigned short* qr = qb + n * HS + h * 32;
        unsigned short* kr = kb + n * HS + h * 32;
        bf16x8 qv[4], kv[4];
        float sq = 0.f, sk = 0.f;
        #pragma unroll
        for (int j = 0; j < 4; ++j) {
            qv[j] = *(const bf16x8*)(qr + j * 8);
            kv[j] = *(const bf16x8*)(kr + j * 8);
            #pragma unroll
            for (int e = 0; e < 8; ++e) {
                float qf = bf2f((unsigned short)qv[j][e]);
                float kf = bf2f((unsigned short)kv[j][e]);
                sq += qf * qf; sk += kf * kf;
            }
        }
        float rq = rsqrtf(sq) * 0.17677669529663687f;   // fold hd^-0.5 into q
        float rk = rsqrtf(sk);
        #pragma unroll
        for (int j = 0; j < 4; ++j) {
            bf16x8 qo, ko;
            #pragma unroll
            for (int e = 0; e < 8; ++e) {
                qo[e] = (short)f2bf(bf2f((unsigned short)qv[j][e]) * rq);
                ko[e] = (short)f2bf(bf2f((unsigned short)kv[j][e]) * rk);
            }
            *(bf16x8*)(qr + j * 8) = qo;
            *(bf16x8*)(kr + j * 8) = ko;
        }
    }

    // ---- P4: per-head MFMA attention (wave = head) ----
    {
        const int h = wv;
        const int an = l4 >> 1, aw = (l4 & 1) * 4, bmh = l15 >> 3, bmw = l15 & 7;
        bf16x8 aq[4], bk[4];
        #pragma unroll
        for (int mt = 0; mt < 4; ++mt)
            aq[mt] = *(const bf16x8*)(qb + (mt * 16 + l15) * HS + h * 32 + l4 * 8);
        #pragma unroll
        for (int ct = 0; ct < 4; ++ct)
            bk[ct] = *(const bf16x8*)(kb + (ct * 16 + l15) * HS + h * 32 + l4 * 8);
        f32x4 sc[4][4];
        #pragma unroll
        for (int mt = 0; mt < 4; ++mt)
            #pragma unroll
            for (int ct = 0; ct < 4; ++ct)
                sc[mt][ct] = __builtin_amdgcn_mfma_f32_16x16x32_bf16(aq[mt], bk[ct],
                                 (f32x4){0.f, 0.f, 0.f, 0.f}, 0, 0, 0);
        bf16x8 bv[2][2];
        #pragma unroll
        for (int dt = 0; dt < 2; ++dt)
            #pragma unroll
            for (int kk = 0; kk < 2; ++kk)
                bv[dt][kk] = *(const bf16x8*)(vbT + (h * 32 + dt * 16 + l15) * VS + kk * 32 + l4 * 8);

        f32x4 o[4][2];
        #pragma unroll
        for (int mt = 0; mt < 4; ++mt) {
            // bias + row softmax (rows n = mt*16 + l4*4 + r; cols m = ct*16 + l15)
            float mx[4] = {-3e38f, -3e38f, -3e38f, -3e38f};
            #pragma unroll
            for (int ct = 0; ct < 4; ++ct)
                #pragma unroll
                for (int r = 0; r < 4; ++r) {
                    int dgh = mt * 2 + an - ct * 2 - bmh + 7;
                    int dgw = aw + r - bmw + 7;
                    float sv = sc[mt][ct][r] + reltab[h][dgh * 15 + dgw];
                    sc[mt][ct][r] = sv;
                    mx[r] = fmaxf(mx[r], sv);
                }
            #pragma unroll
            for (int r = 0; r < 4; ++r) {
                mx[r] = fmaxf(mx[r], __shfl_xor(mx[r], 1));
                mx[r] = fmaxf(mx[r], __shfl_xor(mx[r], 2));
                mx[r] = fmaxf(mx[r], __shfl_xor(mx[r], 4));
                mx[r] = fmaxf(mx[r], __shfl_xor(mx[r], 8));
            }
            float sum[4] = {0.f, 0.f, 0.f, 0.f};
            #pragma unroll
            for (int ct = 0; ct < 4; ++ct)
                #pragma unroll
                for (int r = 0; r < 4; ++r) {
                    float p = __expf(sc[mt][ct][r] - mx[r]);
                    sc[mt][ct][r] = p;
                    sum[r] += p;
                }
            #pragma unroll
            for (int r = 0; r < 4; ++r) {
                sum[r] += __shfl_xor(sum[r], 1);
                sum[r] += __shfl_xor(sum[r], 2);
                sum[r] += __shfl_xor(sum[r], 4);
                sum[r] += __shfl_xor(sum[r], 8);
                sum[r] = 1.f / sum[r];
            }
            // write normalized P (bf16) into dead q/k halves of head h
            #pragma unroll
            for (int ct = 0; ct < 4; ++ct)
                #pragma unroll
                for (int r = 0; r < 4; ++r) {
                    int n = mt * 16 + l4 * 4 + r;
                    unsigned short pv_ = f2bf(sc[mt][ct][r] * sum[r]);
                    if (ct < 2) qb[n * HS + h * 32 + ct * 16 + l15] = pv_;
                    else        kb[n * HS + h * 32 + (ct - 2) * 16 + l15] = pv_;
                }
            // PV for this row tile
            bf16x8 ap0 = *(const bf16x8*)(qb + (mt * 16 + l15) * HS + h * 32 + l4 * 8);
            bf16x8 ap1 = *(const bf16x8*)(kb + (mt * 16 + l15) * HS + h * 32 + l4 * 8);
            #pragma unroll
            for (int dt = 0; dt < 2; ++dt) {
                f32x4 t0 = __builtin_amdgcn_mfma_f32_16x16x32_bf16(ap0, bv[dt][0],
                               (f32x4){0.f, 0.f, 0.f, 0.f}, 0, 0, 0);
                o[mt][dt] = __builtin_amdgcn_mfma_f32_16x16x32_bf16(ap1, bv[dt][1], t0, 0, 0, 0);
            }
        }
        // o -> hbuf (bf16)
        #pragma unroll
        for (int mt = 0; mt < 4; ++mt)
            #pragma unroll
            for (int dt = 0; dt < 2; ++dt)
                #pragma unroll
                for (int r = 0; r < 4; ++r) {
                    int n = mt * 16 + l4 * 4 + r;
                    hbuf[n * HS + h * 32 + dt * 16 + l15] = f2bf(o[mt][dt][r]);
                }
    }
    __syncthreads();

    // ---- P5: residual + LN2 -> u ----
    if (UMODE == 1) {
        const int c0 = lane * 4;
        float4 lg = *(const float4*)(ln2g + c0);
        float4 lb = *(const float4*)(ln2b + c0);
        for (int n = wv; n < 64; n += 8) {
            const int gh = n >> 3, gw = n & 7;
            const int hh = gh * 16 + hp, ww = gw * 16 + wp;
            size_t pix = ((size_t)(b * 128 + hh) << 7) + ww;
            uint2 g2 = *(const uint2*)(gbuf + pix * 256 + c0);
            uint2 o2 = *(const uint2*)(hbuf + n * HS + c0);
            float v[4];
            v[0] = bflo(g2.x) + bflo(o2.x);
            v[1] = bfhi(g2.x) + bfhi(o2.x);
            v[2] = bflo(g2.y) + bflo(o2.y);
            v[3] = bfhi(g2.y) + bfhi(o2.y);
            float s = v[0] + v[1] + v[2] + v[3];
            float ss = v[0]*v[0] + v[1]*v[1] + v[2]*v[2] + v[3]*v[3];
            #pragma unroll
            for (int off = 32; off >= 1; off >>= 1) {
                s  += __shfl_xor(s, off);
                ss += __shfl_xor(ss, off);
            }
            float mean = s * (1.f / 256.f);
            float var  = ss * (1.f / 256.f) - mean * mean;
            float rstd = rsqrtf(var + 1e-5f);
            float u0 = (v[0] - mean) * rstd * lg.x + lb.x;
            float u1 = (v[1] - mean) * rstd * lg.y + lb.y;
            float u2 = (v[2] - mean) * rstd * lg.z + lb.z;
            float u3 = (v[3] - mean) * rstd * lg.w + lb.w;
            uint2 pk;
            pk.x = (unsigned)f2bf(u0) | ((unsigned)f2bf(u1) << 16);
            pk.y = (unsigned)f2bf(u2) | ((unsigned)f2bf(u3) << 16);
            *(uint2*)(hu + pix * 256 + c0) = pk;
        }
    } else {
        for (int n = wv; n < 64; n += 8) {
            const int gh = n >> 3, gw = n & 7;
            const int hh = gh * 16 + hp, ww = gw * 16 + wp;
            const float* xp = x + ((size_t)(b * 256) * 128 + hh) * 128 + ww;
            float v0 = xp[(size_t)(lane) * 16384]        + bf2f(hbuf[n * HS + lane]);
            float v1 = xp[(size_t)(lane + 64) * 16384]   + bf2f(hbuf[n * HS + lane + 64]);
            float v2 = xp[(size_t)(lane + 128) * 16384]  + bf2f(hbuf[n * HS + lane + 128]);
            float v3 = xp[(size_t)(lane + 192) * 16384]  + bf2f(hbuf[n * HS + lane + 192]);
            float s = v0 + v1 + v2 + v3;
            float ss = v0*v0 + v1*v1 + v2*v2 + v3*v3;
            #pragma unroll
            for (int off = 32; off >= 1; off >>= 1) {
                s  += __shfl_xor(s, off);
                ss += __shfl_xor(ss, off);
            }
            float mean = s * (1.f / 256.f);
            float var  = ss * (1.f / 256.f) - mean * mean;
            float rstd = rsqrtf(var + 1e-5f);
            float vv[4] = {v0, v1, v2, v3};
            #pragma unroll
            for (int j = 0; j < 4; ++j) {
                int c = lane + j * 64;
                float u = (vv[j] - mean) * rstd * ln2g[c] + ln2b[c];
                uout[((size_t)(b * 256 + c) * 128 + hh) * 128 + ww] = u;
            }
        }
    }
}

// ---------------- K3/K4: MFMA implicit-GEMM conv3x3 + BN + GELU --------------
template <int MODE>
__global__ __launch_bounds__(512, 1) void convmm_kernel(
    const unsigned short* __restrict__ src, const unsigned short* __restrict__ wt,
    const float* __restrict__ bng, const float* __restrict__ bnb,
    const float* __restrict__ bnm, const float* __restrict__ bnv,
    unsigned short* __restrict__ dstb, float* __restrict__ dstf,
    const unsigned short* __restrict__ ubuf)
{
    __shared__ unsigned short in_s[180 * 256];   // 92160 B, swizzled
    __shared__ float scl_s[256], sh_s[256];

    const int id = blockIdx.x;
    const int bx = id & 7, by = (id >> 3) & 15, b = id >> 7;
    const int x0 = bx * 16, y0 = by * 8;
    const int t = threadIdx.x, lane = t & 63, wv = t >> 6;
    const int l15 = lane & 15, l4 = lane >> 4;

    if (t < 256) {
        float iv = rsqrtf(bnv[t] + 1e-5f) * bng[t];
        scl_s[t] = iv;
        sh_s[t] = bnb[t] - bnm[t] * iv;
    }

    const char* in_s_base = (const char*)in_s;
    for (int i = t; i < 5760; i += 512) {
        int ip = i >> 5, ch = i & 31;
        int iy = ip / 18, ix = ip - iy * 18;
        int gy = y0 + iy - 1, gx = x0 + ix - 1;
        uint4 v = {0u, 0u, 0u, 0u};
        if ((unsigned)gy < 128u && (unsigned)gx < 128u)
            v = *(const uint4*)(src + (((size_t)(b * 128 + gy) << 7) + gx) * 256 + ch * 8);
        *(uint4*)((char*)in_s + ip * 512 + ((ch * 16) ^ ((ip & 7) << 4))) = v;
    }
    __syncthreads();

    f32x4 acc[2][8];
    #pragma unroll
    for (int o = 0; o < 2; ++o)
        #pragma unroll
        for (int p = 0; p < 8; ++p) acc[o][p] = (f32x4){0.f, 0.f, 0.f, 0.f};

    for (int cic = 0; cic < 8; ++cic) {
        #pragma unroll
        for (int ky = 0; ky < 3; ++ky) {
            #pragma unroll
            for (int kx = 0; kx < 3; ++kx) {
                const unsigned short* wp_ = wt + ((size_t)((ky * 3 + kx) * 256 + (wv << 5) + l15)) * 256
                                               + cic * 32 + l4 * 8;
                bf16x8 wf0 = *(const bf16x8*)(wp_);
                bf16x8 wf1 = *(const bf16x8*)(wp_ + 16 * 256);
                const int cbyte = cic * 64 + l4 * 16;
                #pragma unroll
                for (int pxt = 0; pxt < 8; ++pxt) {
                    int ip = (pxt + ky) * 18 + l15 + kx;
                    bf16x8 bf = *(const bf16x8*)(in_s_base + ip * 512 + (cbyte ^ ((ip & 7) << 4)));
                    acc[0][pxt] = __builtin_amdgcn_mfma_f32_16x16x32_bf16(wf0, bf, acc[0][pxt], 0, 0, 0);
                    acc[1][pxt] = __builtin_amdgcn_mfma_f32_16x16x32_bf16(wf1, bf, acc[1][pxt], 0, 0, 0);
                }
            }
        }
    }

    #pragma unroll
    for (int oct = 0; oct < 2; ++oct) {
        const int ocb = (wv << 5) + oct * 16 + (l4 << 2);
        float scl[4], sh[4];
        #pragma unroll
        for (int r = 0; r < 4; ++r) { scl[r] = scl_s[ocb + r]; sh[r] = sh_s[ocb + r]; }
        #pragma unroll
        for (int pxt = 0; pxt < 8; ++pxt) {
            const int gy = y0 + pxt, gx = x0 + l15;
            const size_t pix = ((size_t)(b * 128 + gy) << 7) + gx;
            if (MODE == 1) {
                float v0 = acc[oct][pxt][0] * scl[0] + sh[0];
                float v1 = acc[oct][pxt][1] * scl[1] + sh[1];
                float v2 = acc[oct][pxt][2] * scl[2] + sh[2];
                float v3 = acc[oct][pxt][3] * scl[3] + sh[3];
                float g0 = 0.5f * v0 * (1.f + erff(v0 * 0.70710678118654752f));
                float g1 = 0.5f * v1 * (1.f + erff(v1 * 0.70710678118654752f));
                float g2 = 0.5f * v2 * (1.f + erff(v2 * 0.70710678118654752f));
                float g3 = 0.5f * v3 * (1.f + erff(v3 * 0.70710678118654752f));
                uint2 pk;
                pk.x = (unsigned)f2bf(g0) | ((unsigned)f2bf(g1) << 16);
                pk.y = (unsigned)f2bf(g2) | ((unsigned)f2bf(g3) << 16);
                *(uint2*)(dstb + pix * 256 + ocb) = pk;
            } else {
                uint2 ur = *(const uint2*)(ubuf + pix * 256 + ocb);
                float res[4] = {bflo(ur.x), bfhi(ur.x), bflo(ur.y), bfhi(ur.y)};
                #pragma unroll
                for (int r = 0; r < 4; ++r) {
                    float v = acc[oct][pxt][r] * scl[r] + sh[r];
                    float ge = 0.5f * v * (1.f + erff(v * 0.70710678118654752f));
                    dstf[(((size_t)(b * 256 + ocb + r)) << 14) + (gy << 7) + gx] = ge + res[r];
                }
            }
        }
    }
}

// ------------------- fallback conv (fp32 VALU direct) ------------------------
template <int MODE>
__global__ __launch_bounds__(256, 2) void conv_bn_gelu_kernel(
    const void* __restrict__ src_, const float* __restrict__ cw,
    const float* __restrict__ bng, const float* __restrict__ bnb,
    const float* __restrict__ bnm, const float* __restrict__ bnv,
    void* __restrict__ dst_, const float* __restrict__ resid)
{
    __shared__ float in_s[32][18][18];
    __shared__ float w_s[32][9][32];

    const int id = blockIdx.x;
    const int txl = id & 7, tyl = (id >> 3) & 7, oct = (id >> 6) & 7, b = id >> 9;
    const int h0 = tyl * 16, w0 = txl * 16;
    const int t = threadIdx.x;
    const int tx = t & 15, tyg = (t >> 4) & 3, ocg = t >> 6;

    float acc[4][8];
    #pragma unroll
    for (int j = 0; j < 4; ++j)
        #pragma unroll
        for (int p = 0; p < 8; ++p) acc[j][p] = 0.f;

    const float* srcf = (const float*)src_;
    const unsigned short* srcb = (const unsigned short*)src_;

    for (int cb = 0; cb < 8; ++cb) {
        for (int idx = t; idx < 10368; idx += 256) {
            int ci = idx / 324; int r = idx - ci * 324;
            int y = r / 18; int xx = r - y * 18;
            int gy = h0 + y - 1, gx = w0 + xx - 1;
            float val = 0.f;
            if (gy >= 0 && gy < 128 && gx >= 0 && gx < 128) {
                size_t gidx = ((size_t)(b * 256 + cb * 32 + ci) * 128 + gy) * 128 + gx;
                val = (MODE == 1) ? srcf[gidx] : bf2f(srcb[gidx]);
            }
            in_s[ci][y][xx] = val;
        }
        for (int idx = t; idx < 9216; idx += 256) {
            int oc = idx / 288; int r = idx - oc * 288;
            int ci = r / 9; int k = r - ci * 9;
            w_s[ci][k][oc] = cw[((size_t)(oct * 32 + oc) * 256 + cb * 32 + ci) * 9 + k];
        }
        __syncthreads();

        #pragma unroll 1
        for (int ci = 0; ci < 32; ++ci) {
            #pragma unroll
            for (int k = 0; k < 9; ++k) {
                const int ky = k / 3, kx = k - ky * 3;
                float4 wa = *(const float4*)&w_s[ci][k][ocg * 8];
                float4 wb = *(const float4*)&w_s[ci][k][ocg * 8 + 4];
                #pragma unroll
                for (int j = 0; j < 4; ++j) {
                    float iv = in_s[ci][tyg + 4 * j + ky][tx + kx];
                    acc[j][0] += iv * wa.x; acc[j][1] += iv * wa.y;
                    acc[j][2] += iv * wa.z; acc[j][3] += iv * wa.w;
                    acc[j][4] += iv * wb.x; acc[j][5] += iv * wb.y;
                    acc[j][6] += iv * wb.z; acc[j][7] += iv * wb.w;
                }
            }
        }
        __syncthreads();
    }

    #pragma unroll
    for (int p = 0; p < 8; ++p) {
        int oc = oct * 32 + ocg * 8 + p;
        float scl = bng[oc] * rsqrtf(bnv[oc] + 1e-5f);
        float sh  = bnb[oc] - bnm[oc] * scl;
        #pragma unroll
        for (int j = 0; j < 4; ++j) {
            int y = h0 + tyg + 4 * j, xx2 = w0 + tx;
            float v = acc[j][p] * scl + sh;
            float ge = 0.5f * v * (1.f + erff(v * 0.70710678118654752f));
            size_t gidx = ((size_t)(b * 256 + oc) * 128 + y) * 128 + xx2;
            if (MODE == 1) ((unsigned short*)dst_)[gidx] = f2bf(ge);
            else           ((float*)dst_)[gidx] = ge + resid[gidx];
        }
    }
}

// --------------------------------- launcher ----------------------------------
extern "C" void kernel_launch(void* const* d_in, const int* in_sizes, int n_in,
                              void* d_out, int out_size, void* d_ws, size_t ws_size,
                              hipStream_t stream)
{
    const float* x    = (const float*)d_in[0];
    const float* ln1g = (const float*)d_in[1];
    const float* ln1b = (const float*)d_in[2];
    const float* qkvw = (const float*)d_in[3];
    const float* relt = (const float*)d_in[4];
    const float* ln2g = (const float*)d_in[5];
    const float* ln2b = (const float*)d_in[6];
    const float* c1w  = (const float*)d_in[7];
    const float* bn1g = (const float*)d_in[8];
    const float* bn1b = (const float*)d_in[9];
    const float* bn1m = (const float*)d_in[10];
    const float* bn1v = (const float*)d_in[11];
    const float* c2w  = (const float*)d_in[12];
    const float* bn2g = (const float*)d_in[13];
    const float* bn2b = (const float*)d_in[14];
    const float* bn2m = (const float*)d_in[15];
    const float* bn2v = (const float*)d_in[16];

    float* out = (float*)d_out;
    char* ws = (char*)d_ws;

    if (ws_size >= ((size_t)134 << 20)) {
        // ---------------- fast path (MFMA everywhere) ----------------
        unsigned short* wbf = (unsigned short*)ws;                        // 384 KB
        unsigned short* wt1 = (unsigned short*)(ws + ((size_t)1 << 20));  // 1.13 MB
        unsigned short* wt2 = (unsigned short*)(ws + ((size_t)3 << 20));  // 1.13 MB
        unsigned short* hu  = (unsigned short*)(ws + ((size_t)5 << 20));  // 64 MiB
        unsigned short* m1  = (unsigned short*)(ws + ((size_t)69 << 20)); // 64 MiB
        unsigned short* gbuf = m1;   // g lives in m1 slot until conv1 overwrites it

        cvt_w_kernel<<<192, 256, 0, stream>>>(qkvw, wbf);
        wcvt_kernel<<<256, 256, 0, stream>>>(c1w, wt1);
        wcvt_kernel<<<256, 256, 0, stream>>>(c2w, wt2);
        gather_ln1_kernel<1><<<2048, 256, 0, stream>>>(x, ln1g, ln1b, hu, gbuf);
        attn2_kernel<1><<<2048, 512, 0, stream>>>(x, hu, gbuf, wbf, relt, ln2g, ln2b, nullptr);
        convmm_kernel<1><<<1024, 512, 0, stream>>>(hu, wt1, bn1g, bn1b, bn1m, bn1v,
                                                   m1, nullptr, nullptr);
        convmm_kernel<2><<<1024, 512, 0, stream>>>(m1, wt2, bn2g, bn2b, bn2m, bn2v,
                                                   nullptr, out, hu);
    } else {
        // ---------------- fallback ----------------
        unsigned short* wbf = (unsigned short*)ws;
        unsigned short* hu  = (unsigned short*)(ws + (512 << 10));
        unsigned short* m1  = hu;   // alias: h dead after attn

        cvt_w_kernel<<<192, 256, 0, stream>>>(qkvw, wbf);
        gather_ln1_kernel<0><<<2048, 256, 0, stream>>>(x, ln1g, ln1b, hu, nullptr);
        attn2_kernel<0><<<2048, 512, 0, stream>>>(x, hu, nullptr, wbf, relt, ln2g, ln2b, out);
        conv_bn_gelu_kernel<1><<<4096, 256, 0, stream>>>(out, c1w, bn1g, bn1b, bn1m, bn1v,
                                                         (void*)m1, nullptr);
        conv_bn_gelu_kernel<2><<<4096, 256, 0, stream>>>((const void*)m1, c2w, bn2g, bn2b, bn2m, bn2v,
                                                         (void*)out, out);
    }
}